// Round 13
// baseline (221.736 us; speedup 1.0000x reference)
//
#include <hip/hip_runtime.h>

typedef __bf16 bf16x8 __attribute__((ext_vector_type(8)));
typedef __bf16 bf16x2 __attribute__((ext_vector_type(2)));
typedef float f32x4 __attribute__((ext_vector_type(4)));
typedef float f32x16 __attribute__((ext_vector_type(16)));
typedef int i32x4 __attribute__((ext_vector_type(4)));

namespace {
constexpr int kNQ = 1024;
constexpr int kNK = 1024;
constexpr int kD = 128;
constexpr int kBK = 32;           // keys per tile
constexpr int kTileElems = 4096;  // 32x128 bf16 = 8 KB per K/V tile image
constexpr float kScaleLog2e = 0.12751742f;  // log2(e)/sqrt(128)
}

__device__ __forceinline__ int packbf(float a, float b) {
    bf16x2 t; t[0] = (__bf16)a; t[1] = (__bf16)b;
    return __builtin_bit_cast(int, t);
}

// Pre-pass (R10 layouts, unchanged): K,V -> bf16 FRAGMENT-ORDER tile images,
// consumed register-direct from global by fa_fwd:
//   chunk ch = i*64 + lane (i = fragment index, lane = hi*32 + key).
// K image (A-operand, i=s=0..7): ch holds K[key][d = s*16 + hi*8 .. +8].
// V image (B-operand, i = db*2+s): ch holds V[k = s*16+hi*8 ..+8][d = db*32+key].
// Block 2048 performs the LPT rank-sort (fused).
__global__ void repack(const float* __restrict__ K, const float* __restrict__ V,
                       const int* __restrict__ VL,
                       __bf16* __restrict__ Kimg, __bf16* __restrict__ Vimg,
                       int* __restrict__ perm) {
    const int blk = blockIdx.x;

    if (blk == 64 * 32) {
        const int t = threadIdx.x;
        if (t < 64) {
            const int v = VL[t];
            int rank = 0;
            for (int j = 0; j < 64; ++j) {
                const int vj = VL[j];
                rank += (vj > v) || (vj == v && j < t);
            }
            perm[rank] = t;
        }
        return;
    }

    const int b = blk >> 5, t = blk & 31;
    if (t * kBK >= VL[b]) return;  // tile never touched by main kernel
    const int tid = threadIdx.x;
    __shared__ float vbuf[32 * 132];

    const size_t tileofs = (size_t)(b * 32 + t) * kTileElems;

    // ---- K: thread (key = tid>>3, s = tid&7) loads K[key][s*16..+16] and
    //      writes chunks s*64+key (hi=0) and s*64+32+key (hi=1).
    {
        const int key = tid >> 3, s = tid & 7;
        const float* src = K + (((size_t)b * kNK + t * kBK + key) * kD + s * 16);
        const f32x4 x0 = *(const f32x4*)(src + 0);
        const f32x4 x1 = *(const f32x4*)(src + 4);
        const f32x4 x2 = *(const f32x4*)(src + 8);
        const f32x4 x3 = *(const f32x4*)(src + 12);
        bf16x8 h0, h1;
        #pragma unroll
        for (int j = 0; j < 4; ++j) {
            h0[j] = (__bf16)x0[j]; h0[4 + j] = (__bf16)x1[j];
            h1[j] = (__bf16)x2[j]; h1[4 + j] = (__bf16)x3[j];
        }
        *(bf16x8*)(Kimg + tileofs + (s * 64 + key) * 8)      = h0;
        *(bf16x8*)(Kimg + tileofs + (s * 64 + 32 + key) * 8) = h1;
    }

    // ---- V: coalesced load to LDS, then transposed fragment-order store ----
    {
        const int r = tid >> 3, col0 = (tid & 7) * 16;
        const float* src = V + (((size_t)b * kNK + t * kBK + r) * kD + col0);
        #pragma unroll
        for (int j = 0; j < 4; ++j) {
            const f32x4 x = *(const f32x4*)(src + j * 4);
            *(f32x4*)&vbuf[r * 132 + col0 + j * 4] = x;
        }
    }
    __syncthreads();
    #pragma unroll
    for (int it = 0; it < 2; ++it) {
        const int ch  = tid + it * 256;
        const int db  = ch >> 7;
        const int s   = (ch >> 6) & 1;
        const int hi  = (ch >> 5) & 1;
        const int key = ch & 31;
        const int d   = db * 32 + key;
        const int k8  = s * 16 + hi * 8;
        bf16x8 h;
        #pragma unroll
        for (int j = 0; j < 8; ++j) h[j] = (__bf16)vbuf[(k8 + j) * 132 + d];
        *(bf16x8*)(Vimg + tileofs + ch * 8) = h;
    }
}

// ===== R12: R10 core + distance-2 K register prefetch =====
// R10's counters quantify the wall: 130 wave-tiles/CU; MfmaUtil 13.7% ==
// 130 x 128cyc / 115Kcyc (pipes fine); per-tile serial ~1700cyc at only
// 2 waves/SIMD. Dominant serial term: operand reloads issued ~300-450cyc
// before use vs ~600cyc L3-hit latency (images marginally exceed per-XCD L2).
// Fix: double-bank K (kr0/kr1), reload 2 tiles ahead (~1300cyc distance);
// V stays single-banked in place (distance ~450, mostly covered).
// Persistent regs ~192 (<256 cap at (256,2)) — R2's spill was at cap 128.
// Static bank indexing via explicit even/odd bodies (rule #20);
// sched_barrier(0) after each reload-issue pins loads against sinking
// (the mechanism that collapsed R7's pipeline).
__global__ __launch_bounds__(256, 2)
void fa_fwd(const float* __restrict__ Q, const int* __restrict__ VL,
            const int* __restrict__ perm, const __bf16* __restrict__ Kimg,
            const __bf16* __restrict__ Vimg, float* __restrict__ O)
{
    const int tid  = threadIdx.x;
    const int wave = tid >> 6;   // 0..3
    const int lane = tid & 63;
    const int key  = lane & 31;
    const int hi   = lane >> 5;

    // snake-LPT over 512 blocks (R10 mapping, unchanged)
    const int i = blockIdx.x;
    const int j = i & 255;
    const int rank = (i >> 8) ? (511 - j) : j;

    const int b  = perm[rank >> 3];
    const int q0 = (rank & 7) * 128 + wave * 32;

    const int valid  = VL[b];
    const int ntiles = (valid + kBK - 1) / kBK;
    const __bf16* kbase = Kimg + (size_t)b * 32 * kTileElems;
    const __bf16* vbase = Vimg + (size_t)b * 32 * kTileElems;
    const int fofs = lane * 8;

    // Q B-frags: qf[s][j] = Q[q0+key][d = s*16 + hi*8 + j]
    bf16x8 qf[8];
    {
        const float* qp = Q + ((size_t)b * kNQ + q0 + key) * kD + hi * 8;
        #pragma unroll
        for (int s = 0; s < 8; ++s) {
            const f32x4 x0 = *(const f32x4*)(qp + s * 16);
            const f32x4 x1 = *(const f32x4*)(qp + s * 16 + 4);
            #pragma unroll
            for (int jj = 0; jj < 4; ++jj) {
                qf[s][jj]     = (__bf16)x0[jj];
                qf[s][4 + jj] = (__bf16)x1[jj];
            }
        }
    }

    // operand banks: K double-banked (distance-2 prefetch), V single in-place.
    // Speculative loads of tiles >= ntiles read mapped-but-stale ws; they are
    // never consumed (loop guards) — same pattern R10 ran correctly.
    bf16x8 kr0[8], kr1[8], vr[8];
    #pragma unroll
    for (int s = 0; s < 8; ++s)
        kr0[s] = *(const bf16x8*)(kbase + s * 512 + fofs);
    {
        const __bf16* kt1 = kbase + kTileElems;
        #pragma unroll
        for (int s = 0; s < 8; ++s)
            kr1[s] = *(const bf16x8*)(kt1 + s * 512 + fofs);
    }
    #pragma unroll
    for (int f = 0; f < 8; ++f)
        vr[f] = *(const bf16x8*)(vbase + f * 512 + fofs);

    // O accumulators: acc_db[r] = O[q=(r&3)+8*(r>>2)+4*hi][d=db*32+key]
    f32x16 acc0, acc1, acc2, acc3;
    #pragma unroll
    for (int r = 0; r < 16; ++r) { acc0[r]=0.f; acc1[r]=0.f; acc2[r]=0.f; acc3[r]=0.f; }
    float lsum = 0.f;

    const int xaddr = (lane ^ 32) << 2;
    const int hi4   = hi << 2;

    // one tile via bank kk; reload kk <- t+2, vr <- t+1 (guarded)
    auto body = [&](bf16x8 (&kk)[8], int t) {
        // ---- S^T = K Q^T ----
        f32x16 sa, sb;
        #pragma unroll
        for (int r = 0; r < 16; ++r) { sa[r] = 0.f; sb[r] = 0.f; }
        __builtin_amdgcn_s_setprio(1);
        #pragma unroll
        for (int s = 0; s < 4; ++s)
            sa = __builtin_amdgcn_mfma_f32_32x32x16_bf16(kk[s], qf[s], sa, 0, 0, 0);
        #pragma unroll
        for (int s = 4; s < 8; ++s)
            sb = __builtin_amdgcn_mfma_f32_32x32x16_bf16(kk[s], qf[s], sb, 0, 0, 0);
        __builtin_amdgcn_s_setprio(0);

        // reload this K bank for t+2 (consumed after a full 2-tile phase)
        if (t + 2 < ntiles) {
            const __bf16* kt = kbase + (size_t)(t + 2) * kTileElems;
            #pragma unroll
            for (int s = 0; s < 8; ++s)
                kk[s] = *(const bf16x8*)(kt + s * 512 + fofs);
        }
        __builtin_amdgcn_sched_barrier(0);  // pin: loads may not sink below

        f32x16 sv = sa + sb;

        const int kb = t * kBK;
        if (kb + kBK > valid) {
            #pragma unroll
            for (int r = 0; r < 16; ++r) {
                const int cr = (r & 3) + 8 * (r >> 2);
                if (kb + cr + hi4 >= valid) sv[r] = -1e30f;
            }
        }

        #pragma unroll
        for (int r = 0; r < 16; ++r) sv[r] = __builtin_amdgcn_exp2f(sv[r] * kScaleLog2e);

        {
            float a0 = sv[0]+sv[1], a1 = sv[2]+sv[3], a2 = sv[4]+sv[5], a3 = sv[6]+sv[7];
            float a4 = sv[8]+sv[9], a5 = sv[10]+sv[11], a6 = sv[12]+sv[13], a7 = sv[14]+sv[15];
            lsum += ((a0+a1)+(a2+a3)) + ((a4+a5)+(a6+a7));
        }

        // pack pairs + cross-half exchange (R10-verified)
        int w[8], pw[8];
        #pragma unroll
        for (int jp = 0; jp < 8; ++jp) w[jp] = packbf(sv[2*jp], sv[2*jp+1]);
        #pragma unroll
        for (int jp = 0; jp < 8; ++jp) pw[jp] = __builtin_amdgcn_ds_bpermute(xaddr, w[jp]);

        i32x4 f0, f1;
        f0[0] = hi ? pw[2] : w[0];
        f0[1] = hi ? pw[3] : w[1];
        f0[2] = hi ? w[2]  : pw[0];
        f0[3] = hi ? w[3]  : pw[1];
        f1[0] = hi ? pw[6] : w[4];
        f1[1] = hi ? pw[7] : w[5];
        f1[2] = hi ? w[6]  : pw[4];
        f1[3] = hi ? w[7]  : pw[5];
        const bf16x8 pfs0 = __builtin_bit_cast(bf16x8, f0);
        const bf16x8 pfs1 = __builtin_bit_cast(bf16x8, f1);

        // ---- O += P V ----
        __builtin_amdgcn_s_setprio(1);
        acc0 = __builtin_amdgcn_mfma_f32_32x32x16_bf16(pfs0, vr[0], acc0, 0, 0, 0);
        acc1 = __builtin_amdgcn_mfma_f32_32x32x16_bf16(pfs0, vr[2], acc1, 0, 0, 0);
        acc2 = __builtin_amdgcn_mfma_f32_32x32x16_bf16(pfs0, vr[4], acc2, 0, 0, 0);
        acc3 = __builtin_amdgcn_mfma_f32_32x32x16_bf16(pfs0, vr[6], acc3, 0, 0, 0);
        acc0 = __builtin_amdgcn_mfma_f32_32x32x16_bf16(pfs1, vr[1], acc0, 0, 0, 0);
        acc1 = __builtin_amdgcn_mfma_f32_32x32x16_bf16(pfs1, vr[3], acc1, 0, 0, 0);
        acc2 = __builtin_amdgcn_mfma_f32_32x32x16_bf16(pfs1, vr[5], acc2, 0, 0, 0);
        acc3 = __builtin_amdgcn_mfma_f32_32x32x16_bf16(pfs1, vr[7], acc3, 0, 0, 0);
        __builtin_amdgcn_s_setprio(0);

        // reload V for t+1 (consumed after next tile's QK+SM, ~450cyc)
        if (t + 1 < ntiles) {
            const __bf16* vt = vbase + (size_t)(t + 1) * kTileElems;
            #pragma unroll
            for (int f = 0; f < 8; ++f)
                vr[f] = *(const bf16x8*)(vt + f * 512 + fofs);
        }
        __builtin_amdgcn_sched_barrier(0);  // pin: loads may not sink below
    };

    int t = 0;
    while (true) {
        body(kr0, t);                    // even tile
        if (t + 1 >= ntiles) break;
        body(kr1, t + 1);                // odd tile
        t += 2;
        if (t >= ntiles) break;
    }

    // ---- epilogue (R10-verified) ----
    const int plb = __builtin_amdgcn_ds_bpermute(xaddr, __builtin_bit_cast(int, lsum));
    const float linv = 1.0f / (lsum + __builtin_bit_cast(float, plb));
    float* ob = O + ((size_t)b * kNQ + q0) * kD;
    const int hib = hi << 4;
    #pragma unroll
    for (int r = 0; r < 16; ++r) {
        const int cr = (r & 3) + 8 * (r >> 2);
        const int iv = __builtin_amdgcn_ds_bpermute((cr << 2) + hib,
                                                    __builtin_bit_cast(int, linv));
        const float inv = __builtin_bit_cast(float, iv);
        const int q = cr + hi4;
        ob[q * kD +   0 + key] = acc0[r] * inv;
        ob[q * kD +  32 + key] = acc1[r] * inv;
        ob[q * kD +  64 + key] = acc2[r] * inv;
        ob[q * kD +  96 + key] = acc3[r] * inv;
    }
}

extern "C" void kernel_launch(void* const* d_in, const int* in_sizes, int n_in,
                              void* d_out, int out_size, void* d_ws, size_t ws_size,
                              hipStream_t stream) {
    const float* Q = (const float*)d_in[0];
    const float* K = (const float*)d_in[1];
    const float* V = (const float*)d_in[2];
    const int*  VL = (const int*)d_in[3];
    float* O = (float*)d_out;

    int* perm = (int*)d_ws;
    __bf16* Kimg = (__bf16*)((char*)d_ws + 4096);
    __bf16* Vimg = (__bf16*)((char*)d_ws + 4096 + (size_t)16 * 1024 * 1024);

    repack<<<dim3(64 * 32 + 1), 256, 0, stream>>>(K, V, VL, Kimg, Vimg, perm);
    fa_fwd<<<dim3(512), 256, 0, stream>>>(Q, VL, perm, Kimg, Vimg, O);
}

// Round 14
// 191.374 us; speedup vs baseline: 1.1587x; 1.1587x over previous
//
#include <hip/hip_runtime.h>

typedef __bf16 bf16x8 __attribute__((ext_vector_type(8)));
typedef __bf16 bf16x2 __attribute__((ext_vector_type(2)));
typedef float f32x4 __attribute__((ext_vector_type(4)));
typedef float f32x16 __attribute__((ext_vector_type(16)));
typedef int i32x4 __attribute__((ext_vector_type(4)));

namespace {
constexpr int kNQ = 1024;
constexpr int kNK = 1024;
constexpr int kD = 128;
constexpr int kB  = 64;
constexpr int kBK = 32;           // keys per tile
constexpr int kTileElems = 4096;  // 32x128 bf16 = 8 KB per K/V tile image
constexpr float kScaleLog2e = 0.12751742f;  // log2(e)/sqrt(128)
}

__device__ __forceinline__ int packbf(float a, float b) {
    bf16x2 t; t[0] = (__bf16)a; t[1] = (__bf16)b;
    return __builtin_bit_cast(int, t);
}

// Pre-pass (R10 layouts, unchanged): K,V -> bf16 FRAGMENT-ORDER tile images,
// consumed register-direct from global by fa_fwd:
//   chunk ch = i*64 + lane (i = fragment index, lane = hi*32 + key).
// K image (A-operand, i=s=0..7): ch holds K[key][d = s*16 + hi*8 .. +8].
// V image (B-operand, i = db*2+s): ch holds V[k = s*16+hi*8 ..+8][d = db*32+key].
// Block 2048 performs the LPT rank-sort (fused).
__global__ void repack(const float* __restrict__ K, const float* __restrict__ V,
                       const int* __restrict__ VL,
                       __bf16* __restrict__ Kimg, __bf16* __restrict__ Vimg,
                       int* __restrict__ perm) {
    const int blk = blockIdx.x;

    if (blk == 64 * 32) {
        const int t = threadIdx.x;
        if (t < 64) {
            const int v = VL[t];
            int rank = 0;
            for (int j = 0; j < 64; ++j) {
                const int vj = VL[j];
                rank += (vj > v) || (vj == v && j < t);
            }
            perm[rank] = t;
        }
        return;
    }

    const int b = blk >> 5, t = blk & 31;
    if (t * kBK >= VL[b]) return;  // tile never touched by main kernel
    const int tid = threadIdx.x;
    __shared__ float vbuf[32 * 132];

    const size_t tileofs = (size_t)(b * 32 + t) * kTileElems;

    // ---- K: thread (key = tid>>3, s = tid&7) loads K[key][s*16..+16] and
    //      writes chunks s*64+key (hi=0) and s*64+32+key (hi=1).
    {
        const int key = tid >> 3, s = tid & 7;
        const float* src = K + (((size_t)b * kNK + t * kBK + key) * kD + s * 16);
        const f32x4 x0 = *(const f32x4*)(src + 0);
        const f32x4 x1 = *(const f32x4*)(src + 4);
        const f32x4 x2 = *(const f32x4*)(src + 8);
        const f32x4 x3 = *(const f32x4*)(src + 12);
        bf16x8 h0, h1;
        #pragma unroll
        for (int j = 0; j < 4; ++j) {
            h0[j] = (__bf16)x0[j]; h0[4 + j] = (__bf16)x1[j];
            h1[j] = (__bf16)x2[j]; h1[4 + j] = (__bf16)x3[j];
        }
        *(bf16x8*)(Kimg + tileofs + (s * 64 + key) * 8)      = h0;
        *(bf16x8*)(Kimg + tileofs + (s * 64 + 32 + key) * 8) = h1;
    }

    // ---- V: coalesced load to LDS, then transposed fragment-order store ----
    {
        const int r = tid >> 3, col0 = (tid & 7) * 16;
        const float* src = V + (((size_t)b * kNK + t * kBK + r) * kD + col0);
        #pragma unroll
        for (int j = 0; j < 4; ++j) {
            const f32x4 x = *(const f32x4*)(src + j * 4);
            *(f32x4*)&vbuf[r * 132 + col0 + j * 4] = x;
        }
    }
    __syncthreads();
    #pragma unroll
    for (int it = 0; it < 2; ++it) {
        const int ch  = tid + it * 256;
        const int db  = ch >> 7;
        const int s   = (ch >> 6) & 1;
        const int hi  = (ch >> 5) & 1;
        const int key = ch & 31;
        const int d   = db * 32 + key;
        const int k8  = s * 16 + hi * 8;
        bf16x8 h;
        #pragma unroll
        for (int j = 0; j < 8; ++j) h[j] = (__bf16)vbuf[(k8 + j) * 132 + d];
        *(bf16x8*)(Vimg + tileofs + ch * 8) = h;
    }
}

// ===== R14: split-K two-pass (R10 core, keys halved across 2 blocks) =====
// Cross-round invariant (R1-R10): wall == max_tiles_per_wave(32) x T_tile
// (~1.6us), structure-independent; no pipe >31%; occupancy-15% tail = the
// heaviest batch's waves finishing alone. Fix: divide the binding term.
// Grid 1024: block = (b, q-chunk128, kpar); kpar half processes <=16 tiles.
// Fixed-max softmax => partials exactly additive: kpar0 numerator -> O,
// kpar1 numerator -> ws, both store partial rowsums l; elementwise combine
// kernel computes (N0+N1)/(l0+l1). No inter-wave handshake (R11's failure
// mode structurally absent). Side benefit: 4096 waves -> up to 16 waves/CU
// (VGPR 104 = 4 waves/SIMD). Per-tile body/core = R10 verified, unchanged.
// R2/R12 lesson respected: only 2 operand banks (kr,vr) live.
__global__ __launch_bounds__(256, 2)
void fa_fwd(const float* __restrict__ Q, const int* __restrict__ VL,
            const int* __restrict__ perm, const __bf16* __restrict__ Kimg,
            const __bf16* __restrict__ Vimg, float* __restrict__ Onum,
            float* __restrict__ Npart, float* __restrict__ Lpart)
{
    const int tid  = threadIdx.x;
    const int wave = tid >> 6;   // 0..3
    const int lane = tid & 63;
    const int key  = lane & 31;
    const int hi   = lane >> 5;

    // snake-LPT over 1024 blocks: ranks {j, 1023-j} pair heavy with light.
    const int i = blockIdx.x;
    const int j = i & 511;
    const int rank = (i >> 9) ? (1023 - j) : j;

    const int b    = perm[rank >> 4];  // 16 items per batch: 8 q-chunks x 2 kpar
    const int sub  = rank & 15;
    const int qc   = sub >> 1;
    const int kpar = sub & 1;
    const int q0   = qc * 128 + wave * 32;

    const int valid  = VL[b];
    const int ntiles = (valid + kBK - 1) / kBK;
    const int nt0    = (ntiles + 1) >> 1;
    const int tbeg   = kpar ? nt0 : 0;
    const int tend   = kpar ? ntiles : nt0;   // may be empty (ntiles==1,kpar==1)

    const __bf16* kbase = Kimg + (size_t)b * 32 * kTileElems;
    const __bf16* vbase = Vimg + (size_t)b * 32 * kTileElems;
    const int fofs = lane * 8;

    // Q B-frags: qf[s][j] = Q[q0+key][d = s*16 + hi*8 + j]
    bf16x8 qf[8];
    {
        const float* qp = Q + ((size_t)b * kNQ + q0 + key) * kD + hi * 8;
        #pragma unroll
        for (int s = 0; s < 8; ++s) {
            const f32x4 x0 = *(const f32x4*)(qp + s * 16);
            const f32x4 x1 = *(const f32x4*)(qp + s * 16 + 4);
            #pragma unroll
            for (int jj = 0; jj < 4; ++jj) {
                qf[s][jj]     = (__bf16)x0[jj];
                qf[s][4 + jj] = (__bf16)x1[jj];
            }
        }
    }

    // operand banks (R10 pattern: single bank each, reloaded in place after
    // last consumer). Speculative loads past tend read mapped ws — never
    // consumed (same pattern R10 ran correctly).
    bf16x8 kr[8], vr[8];
    {
        const __bf16* kt0 = kbase + (size_t)tbeg * kTileElems;
        const __bf16* vt0 = vbase + (size_t)tbeg * kTileElems;
        #pragma unroll
        for (int s = 0; s < 8; ++s) kr[s] = *(const bf16x8*)(kt0 + s * 512 + fofs);
        #pragma unroll
        for (int f = 0; f < 8; ++f) vr[f] = *(const bf16x8*)(vt0 + f * 512 + fofs);
    }

    // numerator accumulators: acc_db[r] = N[q=(r&3)+8*(r>>2)+4*hi][d=db*32+key]
    f32x16 acc0, acc1, acc2, acc3;
    #pragma unroll
    for (int r = 0; r < 16; ++r) { acc0[r]=0.f; acc1[r]=0.f; acc2[r]=0.f; acc3[r]=0.f; }
    float lsum = 0.f;

    const int xaddr = (lane ^ 32) << 2;
    const int hi4   = hi << 2;

    for (int t = tbeg; t < tend; ++t) {
        // ---- S^T = K Q^T ----
        f32x16 sa, sb;
        #pragma unroll
        for (int r = 0; r < 16; ++r) { sa[r] = 0.f; sb[r] = 0.f; }
        __builtin_amdgcn_s_setprio(1);
        #pragma unroll
        for (int s = 0; s < 4; ++s)
            sa = __builtin_amdgcn_mfma_f32_32x32x16_bf16(kr[s], qf[s], sa, 0, 0, 0);
        #pragma unroll
        for (int s = 4; s < 8; ++s)
            sb = __builtin_amdgcn_mfma_f32_32x32x16_bf16(kr[s], qf[s], sb, 0, 0, 0);
        __builtin_amdgcn_s_setprio(0);

        // reload K for t+1 (issued a full SM+PV phase before use)
        if (t + 1 < tend) {
            const __bf16* kt = kbase + (size_t)(t + 1) * kTileElems;
            #pragma unroll
            for (int s = 0; s < 8; ++s) kr[s] = *(const bf16x8*)(kt + s * 512 + fofs);
        }

        f32x16 sv = sa + sb;

        const int kb = t * kBK;
        if (kb + kBK > valid) {
            #pragma unroll
            for (int r = 0; r < 16; ++r) {
                const int cr = (r & 3) + 8 * (r >> 2);
                if (kb + cr + hi4 >= valid) sv[r] = -1e30f;
            }
        }

        #pragma unroll
        for (int r = 0; r < 16; ++r) sv[r] = __builtin_amdgcn_exp2f(sv[r] * kScaleLog2e);

        {
            float a0 = sv[0]+sv[1], a1 = sv[2]+sv[3], a2 = sv[4]+sv[5], a3 = sv[6]+sv[7];
            float a4 = sv[8]+sv[9], a5 = sv[10]+sv[11], a6 = sv[12]+sv[13], a7 = sv[14]+sv[15];
            lsum += ((a0+a1)+(a2+a3)) + ((a4+a5)+(a6+a7));
        }

        // pack pairs + cross-half exchange (R10-verified)
        int w[8], pw[8];
        #pragma unroll
        for (int jp = 0; jp < 8; ++jp) w[jp] = packbf(sv[2*jp], sv[2*jp+1]);
        #pragma unroll
        for (int jp = 0; jp < 8; ++jp) pw[jp] = __builtin_amdgcn_ds_bpermute(xaddr, w[jp]);

        i32x4 f0, f1;
        f0[0] = hi ? pw[2] : w[0];
        f0[1] = hi ? pw[3] : w[1];
        f0[2] = hi ? w[2]  : pw[0];
        f0[3] = hi ? w[3]  : pw[1];
        f1[0] = hi ? pw[6] : w[4];
        f1[1] = hi ? pw[7] : w[5];
        f1[2] = hi ? w[6]  : pw[4];
        f1[3] = hi ? w[7]  : pw[5];
        const bf16x8 pfs0 = __builtin_bit_cast(bf16x8, f0);
        const bf16x8 pfs1 = __builtin_bit_cast(bf16x8, f1);

        // ---- N += P V ----
        __builtin_amdgcn_s_setprio(1);
        acc0 = __builtin_amdgcn_mfma_f32_32x32x16_bf16(pfs0, vr[0], acc0, 0, 0, 0);
        acc1 = __builtin_amdgcn_mfma_f32_32x32x16_bf16(pfs0, vr[2], acc1, 0, 0, 0);
        acc2 = __builtin_amdgcn_mfma_f32_32x32x16_bf16(pfs0, vr[4], acc2, 0, 0, 0);
        acc3 = __builtin_amdgcn_mfma_f32_32x32x16_bf16(pfs0, vr[6], acc3, 0, 0, 0);
        acc0 = __builtin_amdgcn_mfma_f32_32x32x16_bf16(pfs1, vr[1], acc0, 0, 0, 0);
        acc1 = __builtin_amdgcn_mfma_f32_32x32x16_bf16(pfs1, vr[3], acc1, 0, 0, 0);
        acc2 = __builtin_amdgcn_mfma_f32_32x32x16_bf16(pfs1, vr[5], acc2, 0, 0, 0);
        acc3 = __builtin_amdgcn_mfma_f32_32x32x16_bf16(pfs1, vr[7], acc3, 0, 0, 0);
        __builtin_amdgcn_s_setprio(0);

        // reload V for t+1
        if (t + 1 < tend) {
            const __bf16* vt = vbase + (size_t)(t + 1) * kTileElems;
            #pragma unroll
            for (int f = 0; f < 8; ++f) vr[f] = *(const bf16x8*)(vt + f * 512 + fofs);
        }
    }

    // ---- epilogue: store PARTIAL numerator + partial rowsum (no divide) ----
    // full partial rowsum for q=key: add partner half's partial
    const int plb = __builtin_amdgcn_ds_bpermute(xaddr, __builtin_bit_cast(int, lsum));
    const float lrow = lsum + __builtin_bit_cast(float, plb);
    if (hi == 0) Lpart[((size_t)kpar * kB + b) * kNQ + q0 + key] = lrow;

    float* nb = (kpar ? Npart : Onum) + ((size_t)b * kNQ + q0) * kD;
    #pragma unroll
    for (int r = 0; r < 16; ++r) {
        const int cr = (r & 3) + 8 * (r >> 2);
        const int q = cr + hi4;
        nb[q * kD +   0 + key] = acc0[r];
        nb[q * kD +  32 + key] = acc1[r];
        nb[q * kD +  64 + key] = acc2[r];
        nb[q * kD +  96 + key] = acc3[r];
    }
}

// Elementwise combine: O = (N0 + N1) / (l0 + l1). Fully coalesced f32x4.
__global__ __launch_bounds__(256)
void combine(float* __restrict__ O, const float* __restrict__ Npart,
             const float* __restrict__ Lpart)
{
    const size_t idx = (size_t)blockIdx.x * 256 + threadIdx.x;
    // 64*1024*128 f32 = 2^21 f32x4 chunks; each thread handles 4 consecutive.
    #pragma unroll
    for (int u = 0; u < 4; ++u) {
        const size_t c = idx * 4 + u;            // f32x4 index
        const size_t row = c >> 5;               // 32 chunks per 128-d row
        const float l = Lpart[row] + Lpart[(size_t)kB * kNQ + row];
        const float inv = 1.0f / l;
        f32x4 n0 = *((const f32x4*)O + c);
        const f32x4 n1 = *((const f32x4*)Npart + c);
        #pragma unroll
        for (int e = 0; e < 4; ++e) n0[e] = (n0[e] + n1[e]) * inv;
        *((f32x4*)O + c) = n0;
    }
}

extern "C" void kernel_launch(void* const* d_in, const int* in_sizes, int n_in,
                              void* d_out, int out_size, void* d_ws, size_t ws_size,
                              hipStream_t stream) {
    const float* Q = (const float*)d_in[0];
    const float* K = (const float*)d_in[1];
    const float* V = (const float*)d_in[2];
    const int*  VL = (const int*)d_in[3];
    float* O = (float*)d_out;

    int* perm    = (int*)d_ws;
    __bf16* Kimg = (__bf16*)((char*)d_ws + 4096);
    __bf16* Vimg = (__bf16*)((char*)d_ws + 4096 + (size_t)16 * 1024 * 1024);
    float* Npart = (float*)((char*)d_ws + 4096 + (size_t)32 * 1024 * 1024);
    float* Lpart = (float*)((char*)d_ws + 4096 + (size_t)32 * 1024 * 1024
                            + (size_t)kB * kNQ * kD * sizeof(float));

    repack<<<dim3(64 * 32 + 1), 256, 0, stream>>>(K, V, VL, Kimg, Vimg, perm);
    fa_fwd<<<dim3(1024), 256, 0, stream>>>(Q, VL, perm, Kimg, Vimg, O, Npart, Lpart);
    combine<<<dim3(2048), 256, 0, stream>>>(O, Npart, Lpart);
}

// Round 15
// 173.048 us; speedup vs baseline: 1.2814x; 1.1059x over previous
//
#include <hip/hip_runtime.h>

typedef __bf16 bf16x8 __attribute__((ext_vector_type(8)));
typedef __bf16 bf16x2 __attribute__((ext_vector_type(2)));
typedef float f32x4 __attribute__((ext_vector_type(4)));
typedef float f32x16 __attribute__((ext_vector_type(16)));
typedef int i32x4 __attribute__((ext_vector_type(4)));

namespace {
constexpr int kNQ = 1024;
constexpr int kNK = 1024;
constexpr int kD = 128;
constexpr int kBK = 32;           // keys per tile
constexpr int kTileElems = 4096;  // 32x128 bf16 = 8 KB per staged tile
constexpr float kScaleLog2e = 0.12751742f;  // log2(e)/sqrt(128)
}

__device__ __forceinline__ int packbf(float a, float b) {
    bf16x2 t; t[0] = (__bf16)a; t[1] = (__bf16)b;
    return __builtin_bit_cast(int, t);
}

// ===== R15: fully-fused single kernel =====
// Ledger across R1-R14: total - fa_fwd == 113-118us CONSTANT (repack +
// dispatch gaps + image HBM round-trips) while fa_fwd itself is pinned at
// ~48-55us across 7 structures (throughput/TLP/balance all falsified as
// limiters). This round attacks the unmeasured 116us: ONE kernel, no
// pre-pass, no images, no workspace. K/V are converted f32->bf16 in-kernel
// via block-shared LDS staging (conversion can't be per-wave: cvt-at-reload
// stalls = R3's 70us; raw-f32 carry spills = R2/R12) — staged once per
// block per tile, amortized over 4 waves, double-buffered, ONE barrier per
// tile with T14 async-split (issue loads(t+1) -> compute(t) -> vmcnt(0) ->
// cvt+write(t+1) -> barrier). Race-free: write(t+1) targets buf (t+1)&1,
// compute(t) reads t&1; the barrier at iter end orders every write(t+1)
// before any read at iter t+1; a laggard still in compute(t) is safe (other
// buffer). Compute core + epilogue = R10 verified, byte-identical semantics.
// LPT sort inlined (64-lane rank sort, ~1Kcyc/block, saves its dispatch).
__global__ __launch_bounds__(256, 2)
void fa_fused(const float* __restrict__ Q, const float* __restrict__ K,
              const float* __restrict__ V, const int* __restrict__ VL,
              float* __restrict__ O)
{
    __shared__ __align__(16) __bf16 kls[2][kTileElems];  // 16 KB
    __shared__ __align__(16) __bf16 vls[2][kTileElems];  // 16 KB

    const int tid  = threadIdx.x;
    const int wave = tid >> 6;   // 0..3
    const int lane = tid & 63;
    const int key  = lane & 31;
    const int hi   = lane >> 5;

    // ---- inline LPT: rank batches by valid_len desc (each wave redundant) ----
    // lane t holds VL[t]; rank via 64 bpermute pulls; ds_permute scatters
    // batch-ids into rank order; one bpermute pulls this block's batch.
    const int i = blockIdx.x;
    const int jj_ = i & 255;
    const int rank = (i >> 8) ? (511 - jj_) : jj_;   // snake pairing
    int b;
    {
        const int myv = VL[lane];
        int rk = 0;
        #pragma unroll
        for (int j = 0; j < 64; ++j) {
            const int vj = __builtin_amdgcn_ds_bpermute(j << 2, myv);
            rk += (vj > myv) || (vj == myv && j < lane);
        }
        const int inv = __builtin_amdgcn_ds_permute(rk << 2, lane);  // lane r: batch
        b = __builtin_amdgcn_ds_bpermute((rank >> 3) << 2, inv);     // uniform
    }
    const int q0 = (rank & 7) * 128 + wave * 32;

    const int valid  = VL[b];
    const int ntiles = (valid + kBK - 1) / kBK;
    const float* Kb = K + (size_t)b * kNK * kD;
    const float* Vb = V + (size_t)b * kNK * kD;

    // ---- staging thread->chunk params (2 chunks each for K and V) ----
    // K image chunk ch = s*64 + hi*32 + key  holds K[key][s*16+hi*8 .. +8]
    // V image chunk ch = (db*2+s)*64 + hi*32 + key holds V[s*16+hi*8+j][db*32+key]
    const int cha = tid, chb = tid + 256;
    const int ka_off = (cha & 31) * kD + ((cha >> 6) * 16 + ((cha >> 5) & 1) * 8);
    const int kb_off = (chb & 31) * kD + ((chb >> 6) * 16 + ((chb >> 5) & 1) * 8);
    const int va_row = ((cha >> 6) & 1) * 16 + ((cha >> 5) & 1) * 8;  // k8
    const int va_col = (cha >> 7) * 32 + (cha & 31);                  // d
    const int vb_row = ((chb >> 6) & 1) * 16 + ((chb >> 5) & 1) * 8;
    const int vb_col = (chb >> 7) * 32 + (chb & 31);

    float kraw[16];   // 2 K-chunks x 8 f32
    float vraw[16];   // 2 V-chunks x 8 f32

    auto stage_issue = [&](int t) {
        const float* Kt = Kb + (size_t)t * kBK * kD;
        const float* Vt = Vb + (size_t)t * kBK * kD;
        {
            const f32x4 x0 = *(const f32x4*)(Kt + ka_off);
            const f32x4 x1 = *(const f32x4*)(Kt + ka_off + 4);
            const f32x4 x2 = *(const f32x4*)(Kt + kb_off);
            const f32x4 x3 = *(const f32x4*)(Kt + kb_off + 4);
            #pragma unroll
            for (int e = 0; e < 4; ++e) {
                kraw[e] = x0[e]; kraw[4 + e] = x1[e];
                kraw[8 + e] = x2[e]; kraw[12 + e] = x3[e];
            }
        }
        #pragma unroll
        for (int j = 0; j < 8; ++j)
            vraw[j] = Vt[(va_row + j) * kD + va_col];
        #pragma unroll
        for (int j = 0; j < 8; ++j)
            vraw[8 + j] = Vt[(vb_row + j) * kD + vb_col];
    };

    auto stage_write = [&](int bufi) {
        bf16x8 h;
        #pragma unroll
        for (int e = 0; e < 8; ++e) h[e] = (__bf16)kraw[e];
        *(bf16x8*)&kls[bufi][cha * 8] = h;
        #pragma unroll
        for (int e = 0; e < 8; ++e) h[e] = (__bf16)kraw[8 + e];
        *(bf16x8*)&kls[bufi][chb * 8] = h;
        i32x4 p;
        p[0] = packbf(vraw[0], vraw[1]); p[1] = packbf(vraw[2], vraw[3]);
        p[2] = packbf(vraw[4], vraw[5]); p[3] = packbf(vraw[6], vraw[7]);
        *(i32x4*)&vls[bufi][cha * 8] = p;
        p[0] = packbf(vraw[8], vraw[9]);  p[1] = packbf(vraw[10], vraw[11]);
        p[2] = packbf(vraw[12], vraw[13]); p[3] = packbf(vraw[14], vraw[15]);
        *(i32x4*)&vls[bufi][chb * 8] = p;
    };

    // ---- prologue: stage tile 0; Q fragments ----
    stage_issue(0);

    // Q B-frags: qf[s][j] = Q[q0+key][d = s*16 + hi*8 + j]
    bf16x8 qf[8];
    {
        const float* qp = Q + ((size_t)b * kNQ + q0 + key) * kD + hi * 8;
        #pragma unroll
        for (int s = 0; s < 8; ++s) {
            const f32x4 x0 = *(const f32x4*)(qp + s * 16);
            const f32x4 x1 = *(const f32x4*)(qp + s * 16 + 4);
            #pragma unroll
            for (int e = 0; e < 4; ++e) {
                qf[s][e]     = (__bf16)x0[e];
                qf[s][4 + e] = (__bf16)x1[e];
            }
        }
    }
    asm volatile("s_waitcnt vmcnt(0)" ::: "memory");
    stage_write(0);
    __builtin_amdgcn_s_barrier();

    // O accumulators: acc_db[r] = O[q=(r&3)+8*(r>>2)+4*hi][d=db*32+key]
    f32x16 acc0, acc1, acc2, acc3;
    #pragma unroll
    for (int r = 0; r < 16; ++r) { acc0[r]=0.f; acc1[r]=0.f; acc2[r]=0.f; acc3[r]=0.f; }
    float lsum = 0.f;

    const int xaddr = (lane ^ 32) << 2;
    const int hi4   = hi << 2;
    const int fofs  = lane * 8;

    for (int t = 0; t < ntiles; ++t) {
        if (t + 1 < ntiles) stage_issue(t + 1);  // raw loads fly over compute(t)

        const __bf16* kbuf = kls[t & 1];
        const __bf16* vbuf = vls[t & 1];

        // ---- S^T = K Q^T (R10 core) ----
        f32x16 sa, sb;
        #pragma unroll
        for (int r = 0; r < 16; ++r) { sa[r] = 0.f; sb[r] = 0.f; }
        __builtin_amdgcn_s_setprio(1);
        #pragma unroll
        for (int s = 0; s < 4; ++s) {
            const bf16x8 kf = *(const bf16x8*)&kbuf[s * 512 + fofs];
            sa = __builtin_amdgcn_mfma_f32_32x32x16_bf16(kf, qf[s], sa, 0, 0, 0);
        }
        #pragma unroll
        for (int s = 4; s < 8; ++s) {
            const bf16x8 kf = *(const bf16x8*)&kbuf[s * 512 + fofs];
            sb = __builtin_amdgcn_mfma_f32_32x32x16_bf16(kf, qf[s], sb, 0, 0, 0);
        }
        __builtin_amdgcn_s_setprio(0);
        f32x16 sv = sa + sb;

        const int kb = t * kBK;
        if (kb + kBK > valid) {
            #pragma unroll
            for (int r = 0; r < 16; ++r) {
                const int cr = (r & 3) + 8 * (r >> 2);
                if (kb + cr + hi4 >= valid) sv[r] = -1e30f;
            }
        }

        #pragma unroll
        for (int r = 0; r < 16; ++r) sv[r] = __builtin_amdgcn_exp2f(sv[r] * kScaleLog2e);

        {
            float a0 = sv[0]+sv[1], a1 = sv[2]+sv[3], a2 = sv[4]+sv[5], a3 = sv[6]+sv[7];
            float a4 = sv[8]+sv[9], a5 = sv[10]+sv[11], a6 = sv[12]+sv[13], a7 = sv[14]+sv[15];
            lsum += ((a0+a1)+(a2+a3)) + ((a4+a5)+(a6+a7));
        }

        // pack pairs + cross-half exchange (R10-verified)
        int w[8], pw[8];
        #pragma unroll
        for (int jp = 0; jp < 8; ++jp) w[jp] = packbf(sv[2*jp], sv[2*jp+1]);
        #pragma unroll
        for (int jp = 0; jp < 8; ++jp) pw[jp] = __builtin_amdgcn_ds_bpermute(xaddr, w[jp]);

        i32x4 f0, f1;
        f0[0] = hi ? pw[2] : w[0];
        f0[1] = hi ? pw[3] : w[1];
        f0[2] = hi ? w[2]  : pw[0];
        f0[3] = hi ? w[3]  : pw[1];
        f1[0] = hi ? pw[6] : w[4];
        f1[1] = hi ? pw[7] : w[5];
        f1[2] = hi ? w[6]  : pw[4];
        f1[3] = hi ? w[7]  : pw[5];
        const bf16x8 pfs0 = __builtin_bit_cast(bf16x8, f0);
        const bf16x8 pfs1 = __builtin_bit_cast(bf16x8, f1);

        // ---- O += P V ----
        __builtin_amdgcn_s_setprio(1);
        {
            const bf16x8 v0 = *(const bf16x8*)&vbuf[0 * 512 + fofs];
            const bf16x8 v2 = *(const bf16x8*)&vbuf[2 * 512 + fofs];
            const bf16x8 v4 = *(const bf16x8*)&vbuf[4 * 512 + fofs];
            const bf16x8 v6 = *(const bf16x8*)&vbuf[6 * 512 + fofs];
            acc0 = __builtin_amdgcn_mfma_f32_32x32x16_bf16(pfs0, v0, acc0, 0, 0, 0);
            acc1 = __builtin_amdgcn_mfma_f32_32x32x16_bf16(pfs0, v2, acc1, 0, 0, 0);
            acc2 = __builtin_amdgcn_mfma_f32_32x32x16_bf16(pfs0, v4, acc2, 0, 0, 0);
            acc3 = __builtin_amdgcn_mfma_f32_32x32x16_bf16(pfs0, v6, acc3, 0, 0, 0);
            const bf16x8 v1 = *(const bf16x8*)&vbuf[1 * 512 + fofs];
            const bf16x8 v3 = *(const bf16x8*)&vbuf[3 * 512 + fofs];
            const bf16x8 v5 = *(const bf16x8*)&vbuf[5 * 512 + fofs];
            const bf16x8 v7 = *(const bf16x8*)&vbuf[7 * 512 + fofs];
            acc0 = __builtin_amdgcn_mfma_f32_32x32x16_bf16(pfs1, v1, acc0, 0, 0, 0);
            acc1 = __builtin_amdgcn_mfma_f32_32x32x16_bf16(pfs1, v3, acc1, 0, 0, 0);
            acc2 = __builtin_amdgcn_mfma_f32_32x32x16_bf16(pfs1, v5, acc2, 0, 0, 0);
            acc3 = __builtin_amdgcn_mfma_f32_32x32x16_bf16(pfs1, v7, acc3, 0, 0, 0);
        }
        __builtin_amdgcn_s_setprio(0);

        // ---- write next tile's staging (raw loads landed under compute) ----
        if (t + 1 < ntiles) {
            asm volatile("s_waitcnt vmcnt(0)" ::: "memory");
            stage_write((t + 1) & 1);
        }
        __builtin_amdgcn_s_barrier();
    }

    // ---- epilogue (R10-verified) ----
    const int plb = __builtin_amdgcn_ds_bpermute(xaddr, __builtin_bit_cast(int, lsum));
    const float linv = 1.0f / (lsum + __builtin_bit_cast(float, plb));
    float* ob = O + ((size_t)b * kNQ + q0) * kD;
    const int hib = hi << 4;
    #pragma unroll
    for (int r = 0; r < 16; ++r) {
        const int cr = (r & 3) + 8 * (r >> 2);
        const int iv = __builtin_amdgcn_ds_bpermute((cr << 2) + hib,
                                                    __builtin_bit_cast(int, linv));
        const float inv = __builtin_bit_cast(float, iv);
        const int q = cr + hi4;
        ob[q * kD +   0 + key] = acc0[r] * inv;
        ob[q * kD +  32 + key] = acc1[r] * inv;
        ob[q * kD +  64 + key] = acc2[r] * inv;
        ob[q * kD +  96 + key] = acc3[r] * inv;
    }
}

extern "C" void kernel_launch(void* const* d_in, const int* in_sizes, int n_in,
                              void* d_out, int out_size, void* d_ws, size_t ws_size,
                              hipStream_t stream) {
    const float* Q = (const float*)d_in[0];
    const float* K = (const float*)d_in[1];
    const float* V = (const float*)d_in[2];
    const int*  VL = (const int*)d_in[3];
    float* O = (float*)d_out;

    fa_fused<<<dim3(512), 256, 0, stream>>>(Q, K, V, VL, O);
}